// Round 9
// baseline (153.289 us; speedup 1.0000x reference)
//
#include <hip/hip_runtime.h>
#include <hip/hip_bf16.h>
#include <stdint.h>

typedef __bf16 bf16;
typedef __bf16 bf16x4 __attribute__((ext_vector_type(4)));
typedef __bf16 bf16x8 __attribute__((ext_vector_type(8)));
typedef float f32x4 __attribute__((ext_vector_type(4)));

#define MFMA(a, b, c) __builtin_amdgcn_mfma_f32_16x16x32_bf16(a, b, c, 0, 0, 0)
#define GL(p) ((const __attribute__((address_space(1))) void*)(p))
#define SH(p) ((__attribute__((address_space(3))) void*)(p))

// ---- prep: ONLY what k1c needs (small transposes + bias concat) ----
__device__ inline void tp(const float* W, bf16* WT, int id, int shiftK, int N) {
  int K = 1 << shiftK;
  int n = id >> shiftK;
  int k = id & (K - 1);
  WT[id] = (bf16)W[(size_t)k * N + n];
}

__global__ __launch_bounds__(256) void prep_all(
    const float* __restrict__ Wpre, const float* __restrict__ Wloc,
    const float* __restrict__ Wgcn, const float* __restrict__ Wpost,
    bf16* __restrict__ WpreLocT, bf16* __restrict__ Wg0T, bf16* __restrict__ Wg1T,
    bf16* __restrict__ WpostT,
    const float* __restrict__ bpre, const float* __restrict__ bloc,
    float* __restrict__ biasPL) {
  int blk = blockIdx.x;
  int tid = threadIdx.x;
  if (blk < 448) {                       // small transposes
    int id = blk * 256 + tid;
    if (id < 16384) { tp(Wpre, WpreLocT, id, 7, 128); return; } id -= 16384;
    if (id < 32768) { tp(Wloc, WpreLocT + 16384, id, 7, 256); return; } id -= 32768;
    if (id < 16384) { tp(Wgcn, Wg0T, id, 7, 128); return; } id -= 16384;
    if (id < 16384) { tp(Wgcn + 16384, Wg1T, id, 7, 128); return; } id -= 16384;
    tp(Wpost, WpostT, id, 7, 256);
    return;
  }
  // bias concat
  if (tid < 128) biasPL[tid] = bpre[tid];
  biasPL[128 + tid] = bloc[tid];
}

// ---- K1 + collapsed GCN chain (ends at g); blocks >= 768 do deferred prep ----
__global__ __launch_bounds__(256, 4) void k1c(
    const float* __restrict__ obs, const bf16* __restrict__ WpreLocT,
    const float* __restrict__ biasPL,
    const bf16* __restrict__ Wg0T, const bf16* __restrict__ Wg1T,
    const bf16* __restrict__ WpostT, const float* __restrict__ b_gcn,
    const float* __restrict__ b_post,
    bf16* __restrict__ gB, bf16* __restrict__ loc,
    const float* __restrict__ W1, const float* __restrict__ W2,
    bf16* __restrict__ W1T, bf16* __restrict__ W2T,
    const float* __restrict__ W3, bf16* __restrict__ W3bT,
    float* __restrict__ outq) {
  __shared__ bf16 smem[16384];   // 2 x (A 4096 + B 4096); also transpose tile

  const int tid = threadIdx.x;
  int id = blockIdx.x;

  if (id >= 768) {                       // deferred prep (hidden in k1c slack)
    int blk = id - 768;
    if (blk < 128) {                     // tiled transpose W1/W2 (512x512 each)
      bf16* tile = smem;                 // 64 x 68
      const float* W = (blk < 64) ? W1 : W2;
      bf16* WT = (blk < 64) ? W1T : W2T;
      int t = blk & 63;
      int tk0 = (t >> 3) * 64, tn0 = (t & 7) * 64;
#pragma unroll
      for (int p = 0; p < 4; p++) {
        int kr = p * 16 + (tid >> 4), nc = (tid & 15) * 4;
        float4 f = *(const float4*)(W + (size_t)(tk0 + kr) * 512 + tn0 + nc);
        bf16x4 v; v[0] = (bf16)f.x; v[1] = (bf16)f.y; v[2] = (bf16)f.z; v[3] = (bf16)f.w;
        *(bf16x4*)&tile[kr * 68 + nc] = v;
      }
      __syncthreads();
#pragma unroll
      for (int p = 0; p < 4; p++) {
        int nr = p * 16 + (tid >> 4), kc = (tid & 15) * 4;
        bf16x4 v;
#pragma unroll
        for (int i = 0; i < 4; i++) v[i] = tile[(kc + i) * 68 + nr];
        *(bf16x4*)(WT + (size_t)(tn0 + nr) * 512 + tk0 + kc) = v;
      }
      return;
    }
    blk -= 128;
    if (blk == 0) {                      // W3 hi/lo B-fragment layout [16][512]
#pragma unroll
      for (int i = 0; i < 32; i++) {
        int id2 = i * 256 + tid;         // 8192 ids
        int n = id2 >> 9, k = id2 & 511;
        float w = (n < 8) ? W3[(size_t)k * 8 + n] : 0.f;
        bf16 hi = (bf16)w;
        W3bT[id2] = hi;
        W3bT[8192 + id2] = (bf16)(w - (float)hi);
      }
      return;
    }
    blk -= 1;
    // zero d_out: 64 blocks x 256 threads x 4 float4 = 262144 floats
    float4 z = {0.f, 0.f, 0.f, 0.f};
#pragma unroll
    for (int i = 0; i < 4; i++)
      ((float4*)outq)[(size_t)blk * 1024 + i * 256 + tid] = z;
    return;
  }

  const int s = id >> 3;
  const int n_idx = s % 3;
  const int m0 = ((id & 7) + 8 * (s / 3)) * 128;
  const int n0 = n_idx * 128;

  f32x4 acc[4][4] = {};
  const int lane = tid & 63, wave = tid >> 6;
  const int wm = (wave >> 1) * 64, wn = (wave & 1) * 64;
  const int lm = lane & 15, quad = lane >> 4;

  float4 pa[4];                          // A prefetch regs (2 chunks x 2 float4)

  auto loadA = [&](int kt) {
#pragma unroll
    for (int it = 0; it < 2; it++) {
      int idx = it * 256 + tid;
      int row = idx >> 2;
      int c = idx & 3;
      int cv = c ^ ((row >> 1) & 3);
      const float* src = obs + (size_t)(m0 + row) * 128 + kt * 32 + cv * 8;
      pa[it * 2] = *(const float4*)src;
      pa[it * 2 + 1] = *(const float4*)(src + 4);
    }
  };
  auto stageB = [&](int kt, int buf) {
    bf16* Bd = smem + buf * 8192 + 4096;
#pragma unroll
    for (int it = 0; it < 2; it++) {
      int idx = it * 256 + tid;
      int row = idx >> 2;
      int c = idx & 3;
      int cv = c ^ ((row >> 1) & 3);
      const bf16* gb = WpreLocT + (size_t)(n0 + row) * 128 + kt * 32 + cv * 8;
      __builtin_amdgcn_global_load_lds(GL(gb), SH(&Bd[(idx & ~63) * 8]), 16, 0, 0);
    }
  };
  auto commitA = [&](int buf) {
    bf16* Ad = smem + buf * 8192;
#pragma unroll
    for (int it = 0; it < 2; it++) {
      int idx = it * 256 + tid;
      int row = idx >> 2;
      int c = idx & 3;
      float4 f0 = pa[it * 2], f1 = pa[it * 2 + 1];
      bf16x8 v;
      v[0] = (bf16)f0.x; v[1] = (bf16)f0.y; v[2] = (bf16)f0.z; v[3] = (bf16)f0.w;
      v[4] = (bf16)f1.x; v[5] = (bf16)f1.y; v[6] = (bf16)f1.z; v[7] = (bf16)f1.w;
      *(bf16x8*)&Ad[row * 32 + c * 8] = v;
    }
  };
  auto compute = [&](int buf) {
    const bf16* Ar = smem + buf * 8192;
    const bf16* Br = smem + buf * 8192 + 4096;
    bf16x8 a[4], b[4];
#pragma unroll
    for (int i = 0; i < 4; i++) {
      int r = wm + lm + i * 16;
      a[i] = *(const bf16x8*)&Ar[r * 32 + ((quad ^ ((r >> 1) & 3)) * 8)];
    }
#pragma unroll
    for (int j = 0; j < 4; j++) {
      int r = wn + lm + j * 16;
      b[j] = *(const bf16x8*)&Br[r * 32 + ((quad ^ ((r >> 1) & 3)) * 8)];
    }
#pragma unroll
    for (int i = 0; i < 4; i++)
#pragma unroll
      for (int j = 0; j < 4; j++)
        acc[i][j] = MFMA(a[i], b[j], acc[i][j]);
  };

  loadA(0); stageB(0, 0); commitA(0);
  __syncthreads();
#pragma unroll
  for (int i = 0; i < 4; ++i) {
    if (i + 1 < 4) { loadA(i + 1); stageB(i + 1, (i + 1) & 1); }
    compute(i & 1);
    if (i + 1 < 4) commitA((i + 1) & 1);
    __syncthreads();
  }

  if (n_idx == 0) {
    bf16* xs = smem;                  // 16 x 136
    bf16* x2 = smem + 2176;           // 16 x 136
    bf16* gS = smem + 4352;           // 16 x 264
#pragma unroll
    for (int i = 0; i < 4; i++) {
      int sl = (wave >> 1) * 4 + i;
#pragma unroll
      for (int j = 0; j < 4; j++) {
        int col = wn + j * 16 + lm;
        float bb = biasPL[col];
        float v = 0.f;
#pragma unroll
        for (int r = 0; r < 4; r++) v += fmaxf(acc[i][j][r] + bb, 0.f);
        v += __shfl_xor(v, 16);
        v += __shfl_xor(v, 32);
        if (quad == 0) xs[sl * 136 + col] = (bf16)(v * 0.0625f);
        else if (quad == 1) xs[(8 + sl) * 136 + col] = (bf16)0.f;
      }
    }
    __syncthreads();
    {  // l0: xs -> x2
      f32x4 c2[2] = {};
#pragma unroll
      for (int ku = 0; ku < 4; ++ku) {
        bf16x8 a = *(const bf16x8*)&xs[lm * 136 + (ku * 4 + quad) * 8];
#pragma unroll
        for (int jn = 0; jn < 2; ++jn) {
          int col = (wave * 2 + jn) * 16 + lm;
          bf16x8 b = *(const bf16x8*)&Wg0T[(size_t)col * 128 + ku * 32 + quad * 8];
          c2[jn] = MFMA(a, b, c2[jn]);
        }
      }
      __syncthreads();
#pragma unroll
      for (int jn = 0; jn < 2; ++jn) {
        int col = (wave * 2 + jn) * 16 + lm;
        float bb = b_gcn[col];
#pragma unroll
        for (int r = 0; r < 4; ++r)
          x2[(quad * 4 + r) * 136 + col] = (bf16)fmaxf(c2[jn][r] + bb, 0.f);
      }
    }
    __syncthreads();
    {  // l1: x2 -> xs
      f32x4 c2[2] = {};
#pragma unroll
      for (int ku = 0; ku < 4; ++ku) {
        bf16x8 a = *(const bf16x8*)&x2[lm * 136 + (ku * 4 + quad) * 8];
#pragma unroll
        for (int jn = 0; jn < 2; ++jn) {
          int col = (wave * 2 + jn) * 16 + lm;
          bf16x8 b = *(const bf16x8*)&Wg1T[(size_t)col * 128 + ku * 32 + quad * 8];
          c2[jn] = MFMA(a, b, c2[jn]);
        }
      }
      __syncthreads();
#pragma unroll
      for (int jn = 0; jn < 2; ++jn) {
        int col = (wave * 2 + jn) * 16 + lm;
        float bb = b_gcn[128 + col];
#pragma unroll
        for (int r = 0; r < 4; ++r)
          xs[(quad * 4 + r) * 136 + col] = (bf16)fmaxf(c2[jn][r] + bb, 0.f);
      }
    }
    __syncthreads();
    {  // l2: xs -> gS
      f32x4 c3[4] = {};
#pragma unroll
      for (int ku = 0; ku < 4; ++ku) {
        bf16x8 a = *(const bf16x8*)&xs[lm * 136 + (ku * 4 + quad) * 8];
#pragma unroll
        for (int jn = 0; jn < 4; ++jn) {
          int col = (wave * 4 + jn) * 16 + lm;
          bf16x8 b = *(const bf16x8*)&WpostT[(size_t)col * 128 + ku * 32 + quad * 8];
          c3[jn] = MFMA(a, b, c3[jn]);
        }
      }
#pragma unroll
      for (int jn = 0; jn < 4; ++jn) {
        int col = (wave * 4 + jn) * 16 + lm;
        float bb = b_post[col];
#pragma unroll
        for (int r = 0; r < 4; ++r)
          gS[(quad * 4 + r) * 264 + col] = (bf16)fmaxf(c3[jn][r] + bb, 0.f);
      }
    }
    __syncthreads();
    {  // store g (8 samples x 256) -> gB; h computed fused in K3 epilogue
      int sample0 = m0 >> 4;
      int row = tid >> 5, col8 = (tid & 31) * 8;
      *(bf16x8*)&gB[(size_t)(sample0 + row) * 256 + col8] =
          *(const bf16x8*)&gS[row * 264 + col8];
    }
  } else {
#pragma unroll
    for (int i = 0; i < 4; i++)
#pragma unroll
      for (int j = 0; j < 4; j++) {
        int col = wn + j * 16 + lm;
        float bb = biasPL[n0 + col];
#pragma unroll
        for (int r = 0; r < 4; r++) {
          int row = wm + i * 16 + quad * 4 + r;
          smem[row * 128 + col] = (bf16)fmaxf(acc[i][j][r] + bb, 0.f);
        }
      }
    __syncthreads();
    const int coff = n0 - 128;
#pragma unroll
    for (int c = 0; c < 8; c++) {
      int ci = c * 256 + tid;
      int row = ci >> 4, col8 = (ci & 15) * 8;
      *(bf16x8*)&loc[(size_t)(m0 + row) * 256 + coff + col8] = *(const bf16x8*)&smem[row * 128 + col8];
    }
  }
}

// ---- K3/K4: 128x128 GEMM, BK=32, explicit LDS double-buffer (proven loop) ----
// K3 (HREP) epilogue: FUSED h — h_s[8][128] = g(8x256) @ W1a colslice + b1
// (16 MFMA, proven k1c h-stage fragment pattern), then z1 = relu(acc + h_s).
// K4 (!HREP) epilogue: MFMA q-head over bank-swizzled z2 LDS tile with W3 split
// hi+lo bf16 (error-compensated), atomicAdd partials across the 4 n-siblings.
template <bool HREP>
__global__ __launch_bounds__(256, 4) void gemm_k(
    const bf16* __restrict__ Ab, const bf16* __restrict__ BT,
    const float* __restrict__ bias, const bf16* __restrict__ gB2,
    bf16* __restrict__ C,
    const bf16* __restrict__ W3bT, const float* __restrict__ b3,
    float* __restrict__ outq) {
  __shared__ bf16 smem[18432];   // 36 KB: 2 x (A 4096 + B 4096) + 4 KB h_s
  float* const h_s = (float*)(smem + 16384);   // [8][128] f32

  const int tid = threadIdx.x;
  const int id = blockIdx.x;
  const int s = id >> 3;
  const int n_idx = s & 3;
  const int m0 = ((id & 7) + 8 * (s >> 2)) * 128;
  const int n0 = n_idx * 128;

  f32x4 acc[4][4] = {};
  const int lane = tid & 63, wave = tid >> 6;
  const int wm = (wave >> 1) * 64, wn = (wave & 1) * 64;
  const int lm = lane & 15, quad = lane >> 4;

  auto stage = [&](int kt, int buf) {
    bf16* Ad = smem + buf * 8192;
    bf16* Bd = smem + buf * 8192 + 4096;
    int k0 = kt * 32;
#pragma unroll
    for (int it = 0; it < 2; it++) {
      int idx = it * 256 + tid;
      int row = idx >> 2;
      int c = idx & 3;
      int cv = c ^ ((row >> 1) & 3);
      int kk = k0 + cv * 8;
      const bf16* ga = HREP ? (Ab + (size_t)(m0 + row) * 256 + kk)
                            : (Ab + (size_t)(m0 + row) * 512 + kk);
      __builtin_amdgcn_global_load_lds(GL(ga), SH(&Ad[(idx & ~63) * 8]), 16, 0, 0);
      const bf16* gb = HREP ? (BT + (size_t)(n0 + row) * 512 + 256 + kk)
                            : (BT + (size_t)(n0 + row) * 512 + kk);
      __builtin_amdgcn_global_load_lds(GL(gb), SH(&Bd[(idx & ~63) * 8]), 16, 0, 0);
    }
  };

  auto compute = [&](int buf) {
    const bf16* Ar = smem + buf * 8192;
    const bf16* Br = smem + buf * 8192 + 4096;
    bf16x8 a[4], b[4];
#pragma unroll
    for (int i = 0; i < 4; i++) {
      int r = wm + lm + i * 16;
      a[i] = *(const bf16x8*)&Ar[r * 32 + ((quad ^ ((r >> 1) & 3)) * 8)];
    }
#pragma unroll
    for (int j = 0; j < 4; j++) {
      int r = wn + lm + j * 16;
      b[j] = *(const bf16x8*)&Br[r * 32 + ((quad ^ ((r >> 1) & 3)) * 8)];
    }
#pragma unroll
    for (int i = 0; i < 4; i++)
#pragma unroll
      for (int j = 0; j < 4; j++)
        acc[i][j] = MFMA(a[i], b[j], acc[i][j]);
  };

  const int NIT = HREP ? 8 : 16;
  stage(0, 0);
  __syncthreads();
#pragma unroll 2
  for (int i = 0; i < NIT; ++i) {
    if (i + 1 < NIT) stage(i + 1, (i + 1) & 1);
    compute(i & 1);
    __syncthreads();
  }

  if (HREP) {
    // fused h: h_s[8][128] = g(8x256) @ W1a(cols n0..n0+128) + b1
    {
      f32x4 hacc[2] = {};
      int sample0 = m0 >> 4;
      int arow = sample0 + lm;
      if (arow > 2047) arow = 2047;      // tail clamp (rows 8-15 unused anyway)
#pragma unroll
      for (int ku = 0; ku < 8; ++ku) {
        bf16x8 a = *(const bf16x8*)&gB2[(size_t)arow * 256 + ku * 32 + quad * 8];
#pragma unroll
        for (int jn = 0; jn < 2; ++jn) {
          int col = n0 + (wave * 2 + jn) * 16 + lm;
          bf16x8 b = *(const bf16x8*)&BT[(size_t)col * 512 + ku * 32 + quad * 8];
          hacc[jn] = MFMA(a, b, hacc[jn]);
        }
      }
      if (quad < 2) {
#pragma unroll
        for (int jn = 0; jn < 2; ++jn) {
          int colr = (wave * 2 + jn) * 16 + lm;
#pragma unroll
          for (int r = 0; r < 4; ++r)
            h_s[(quad * 4 + r) * 128 + colr] = hacc[jn][r] + bias[n0 + colr];
        }
      }
    }
    __syncthreads();
    // z1 = relu(acc + h) staged via LDS for coalesced write
#pragma unroll
    for (int i = 0; i < 4; i++) {
      int rl = (wm >> 4) + i;            // sample-local row 0..7
#pragma unroll
      for (int j = 0; j < 4; j++) {
        float hv = h_s[rl * 128 + wn + j * 16 + lm];
#pragma unroll
        for (int r = 0; r < 4; r++) {
          int row = wm + i * 16 + quad * 4 + r;
          smem[row * 128 + wn + j * 16 + lm] = (bf16)fmaxf(acc[i][j][r] + hv, 0.f);
        }
      }
    }
    __syncthreads();
#pragma unroll
    for (int c = 0; c < 8; c++) {
      int ci = c * 256 + tid;
      int row = ci >> 4, col8 = (ci & 15) * 8;
      *(bf16x8*)&C[(size_t)(m0 + row) * 512 + n0 + col8] = *(const bf16x8*)&smem[row * 128 + col8];
    }
  } else {
    // z2 -> LDS, XOR-swizzled 16B chunks so q-MFMA A-frag reads are conflict-free
#pragma unroll
    for (int i = 0; i < 4; i++)
#pragma unroll
      for (int j = 0; j < 4; j++) {
        int col = wn + j * 16 + lm;
        float bb = bias[n0 + col];
#pragma unroll
        for (int r = 0; r < 4; r++) {
          int row = wm + i * 16 + quad * 4 + r;
          int pc = (col >> 3) ^ (row & 7);
          smem[row * 128 + pc * 8 + (col & 7)] = (bf16)fmaxf(acc[i][j][r] + bb, 0.f);
        }
      }
    __syncthreads();
    bf16x8 w3h[4], w3l[4];
#pragma unroll
    for (int kt = 0; kt < 4; kt++) {
      w3h[kt] = *(const bf16x8*)&W3bT[lm * 512 + n0 + kt * 32 + quad * 8];
      w3l[kt] = *(const bf16x8*)&W3bT[8192 + lm * 512 + n0 + kt * 32 + quad * 8];
    }
    f32x4 qacc[2] = {};
#pragma unroll
    for (int it = 0; it < 2; it++)
#pragma unroll
      for (int kt = 0; kt < 4; kt++) {
        int rr = wave * 32 + it * 16 + lm;
        bf16x8 a = *(const bf16x8*)&smem[rr * 128 + (((kt * 4 + quad) ^ (rr & 7)) * 8)];
        qacc[it] = MFMA(a, w3h[kt], qacc[it]);
        qacc[it] = MFMA(a, w3l[kt], qacc[it]);
      }
    float qb = (n_idx == 0 && lm < 8) ? b3[lm] : 0.f;
    if (lm < 8) {
#pragma unroll
      for (int it = 0; it < 2; it++)
#pragma unroll
        for (int r = 0; r < 4; r++) {
          int row = m0 + wave * 32 + it * 16 + quad * 4 + r;
          atomicAdd(&outq[(size_t)row * 8 + lm], qacc[it][r] + qb);
        }
    }
  }
}

extern "C" void kernel_launch(void* const* d_in, const int* in_sizes, int n_in,
                              void* d_out, int out_size, void* d_ws, size_t ws_size,
                              hipStream_t stream) {
  const float* obs    = (const float*)d_in[0];
  const float* W_pre  = (const float*)d_in[1];
  const float* b_pre  = (const float*)d_in[2];
  const float* W_gcn  = (const float*)d_in[3];
  const float* b_gcn  = (const float*)d_in[4];
  const float* W_post = (const float*)d_in[5];
  const float* b_post = (const float*)d_in[6];
  const float* W_loc  = (const float*)d_in[7];
  const float* b_loc  = (const float*)d_in[8];
  const float* W1     = (const float*)d_in[9];
  const float* b1     = (const float*)d_in[10];
  const float* W2     = (const float*)d_in[11];
  const float* b2     = (const float*)d_in[12];
  const float* W3     = (const float*)d_in[13];
  const float* b3     = (const float*)d_in[14];
  float* out = (float*)d_out;

  char* p = (char*)d_ws;
  auto alloc = [&](size_t bytes) { char* r = p; p += (bytes + 255) & ~(size_t)255; return r; };
  bf16* WpreLocT = (bf16*)alloc(384 * 128 * 2);
  float* biasPL  = (float*)alloc(384 * 4);
  bf16* Wg0T   = (bf16*)alloc(128 * 128 * 2);
  bf16* Wg1T   = (bf16*)alloc(128 * 128 * 2);
  bf16* WpostT = (bf16*)alloc(256 * 128 * 2);
  bf16* W1T    = (bf16*)alloc(512 * 512 * 2);
  bf16* W2T    = (bf16*)alloc(512 * 512 * 2);
  bf16* W3bT   = (bf16*)alloc(2 * 16 * 512 * 2);
  bf16* gB     = (bf16*)alloc((size_t)2048 * 256 * 2);
  bf16* locB   = (bf16*)alloc((size_t)32768 * 256 * 2);
  bf16* z1B    = (bf16*)alloc((size_t)32768 * 512 * 2);

  // P: only k1c-critical prep (small transposes + bias)
  prep_all<<<449, 256, 0, stream>>>(W_pre, W_loc, W_gcn, W_post,
                                    WpreLocT, Wg0T, Wg1T, WpostT,
                                    b_pre, b_loc, biasPL);
  // K1+chain -> g, loc; blocks 768+ do W1/W2 transpose, W3 hi/lo, d_out zero
  k1c<<<961, 256, 0, stream>>>(obs, WpreLocT, biasPL,
                               Wg0T, Wg1T, WpostT, b_gcn, b_post,
                               gB, locB,
                               W1, W2, W1T, W2T, W3, W3bT, out);
  // K3: z1 = relu(loc @ W1b + h) with h fused in epilogue (g @ W1a + b1)
  gemm_k<true><<<1024, 256, 0, stream>>>(locB, W1T, b1, gB, z1B,
                                         nullptr, nullptr, nullptr);
  // K4: z2 = relu(z1 @ W2 + b2) + MFMA q-head, K=512, double-buffered
  gemm_k<false><<<1024, 256, 0, stream>>>(z1B, W2T, b2, nullptr, nullptr,
                                          W3bT, b3, out);
}

// Round 10
// 148.163 us; speedup vs baseline: 1.0346x; 1.0346x over previous
//
#include <hip/hip_runtime.h>
#include <hip/hip_bf16.h>
#include <stdint.h>

typedef __bf16 bf16;
typedef __bf16 bf16x4 __attribute__((ext_vector_type(4)));
typedef __bf16 bf16x8 __attribute__((ext_vector_type(8)));
typedef float f32x4 __attribute__((ext_vector_type(4)));

#define MFMA(a, b, c) __builtin_amdgcn_mfma_f32_16x16x32_bf16(a, b, c, 0, 0, 0)
#define GL(p) ((const __attribute__((address_space(1))) void*)(p))
#define SH(p) ((__attribute__((address_space(3))) void*)(p))
#define BARRIER() do { __builtin_amdgcn_s_barrier(); asm volatile("" ::: "memory"); } while (0)
#define WAIT_LGKM0() do { asm volatile("s_waitcnt lgkmcnt(0)" ::: "memory"); __builtin_amdgcn_sched_barrier(0); } while (0)
#define WAIT_VM(N) do { asm volatile("s_waitcnt vmcnt(" #N ")" ::: "memory"); __builtin_amdgcn_sched_barrier(0); } while (0)

// ---- prep: ONLY what k1c needs (small transposes + bias concat) ----
__device__ inline void tp(const float* W, bf16* WT, int id, int shiftK, int N) {
  int K = 1 << shiftK;
  int n = id >> shiftK;
  int k = id & (K - 1);
  WT[id] = (bf16)W[(size_t)k * N + n];
}

__global__ __launch_bounds__(256) void prep_all(
    const float* __restrict__ Wpre, const float* __restrict__ Wloc,
    const float* __restrict__ Wgcn, const float* __restrict__ Wpost,
    bf16* __restrict__ WpreLocT, bf16* __restrict__ Wg0T, bf16* __restrict__ Wg1T,
    bf16* __restrict__ WpostT,
    const float* __restrict__ bpre, const float* __restrict__ bloc,
    float* __restrict__ biasPL) {
  int blk = blockIdx.x;
  int tid = threadIdx.x;
  if (blk < 448) {                       // small transposes
    int id = blk * 256 + tid;
    if (id < 16384) { tp(Wpre, WpreLocT, id, 7, 128); return; } id -= 16384;
    if (id < 32768) { tp(Wloc, WpreLocT + 16384, id, 7, 256); return; } id -= 32768;
    if (id < 16384) { tp(Wgcn, Wg0T, id, 7, 128); return; } id -= 16384;
    if (id < 16384) { tp(Wgcn + 16384, Wg1T, id, 7, 128); return; } id -= 16384;
    tp(Wpost, WpostT, id, 7, 256);
    return;
  }
  // bias concat
  if (tid < 128) biasPL[tid] = bpre[tid];
  biasPL[128 + tid] = bloc[tid];
}

// ---- K1 + collapsed GCN chain (ends at g); blocks >= 768 do deferred prep ----
__global__ __launch_bounds__(256, 4) void k1c(
    const float* __restrict__ obs, const bf16* __restrict__ WpreLocT,
    const float* __restrict__ biasPL,
    const bf16* __restrict__ Wg0T, const bf16* __restrict__ Wg1T,
    const bf16* __restrict__ WpostT, const float* __restrict__ b_gcn,
    const float* __restrict__ b_post,
    bf16* __restrict__ gB, bf16* __restrict__ loc,
    const float* __restrict__ W1, const float* __restrict__ W2,
    bf16* __restrict__ W1T, bf16* __restrict__ W2T,
    const float* __restrict__ W3, bf16* __restrict__ W3bT,
    float* __restrict__ outq) {
  __shared__ bf16 smem[16384];   // 2 x (A 4096 + B 4096); also transpose tile

  const int tid = threadIdx.x;
  int id = blockIdx.x;

  if (id >= 768) {                       // deferred prep (hidden in k1c slack)
    int blk = id - 768;
    if (blk < 128) {                     // tiled transpose W1/W2 (512x512 each)
      bf16* tile = smem;                 // 64 x 68
      const float* W = (blk < 64) ? W1 : W2;
      bf16* WT = (blk < 64) ? W1T : W2T;
      int t = blk & 63;
      int tk0 = (t >> 3) * 64, tn0 = (t & 7) * 64;
#pragma unroll
      for (int p = 0; p < 4; p++) {
        int kr = p * 16 + (tid >> 4), nc = (tid & 15) * 4;
        float4 f = *(const float4*)(W + (size_t)(tk0 + kr) * 512 + tn0 + nc);
        bf16x4 v; v[0] = (bf16)f.x; v[1] = (bf16)f.y; v[2] = (bf16)f.z; v[3] = (bf16)f.w;
        *(bf16x4*)&tile[kr * 68 + nc] = v;
      }
      __syncthreads();
#pragma unroll
      for (int p = 0; p < 4; p++) {
        int nr = p * 16 + (tid >> 4), kc = (tid & 15) * 4;
        bf16x4 v;
#pragma unroll
        for (int i = 0; i < 4; i++) v[i] = tile[(kc + i) * 68 + nr];
        *(bf16x4*)(WT + (size_t)(tn0 + nr) * 512 + tk0 + kc) = v;
      }
      return;
    }
    blk -= 128;
    if (blk == 0) {                      // W3 hi/lo B-fragment layout [16][512]
#pragma unroll
      for (int i = 0; i < 32; i++) {
        int id2 = i * 256 + tid;         // 8192 ids
        int n = id2 >> 9, k = id2 & 511;
        float w = (n < 8) ? W3[(size_t)k * 8 + n] : 0.f;
        bf16 hi = (bf16)w;
        W3bT[id2] = hi;
        W3bT[8192 + id2] = (bf16)(w - (float)hi);
      }
      return;
    }
    blk -= 1;
    // zero d_out: 64 blocks x 256 threads x 4 float4 = 262144 floats
    float4 z = {0.f, 0.f, 0.f, 0.f};
#pragma unroll
    for (int i = 0; i < 4; i++)
      ((float4*)outq)[(size_t)blk * 1024 + i * 256 + tid] = z;
    return;
  }

  const int s = id >> 3;
  const int n_idx = s % 3;
  const int m0 = ((id & 7) + 8 * (s / 3)) * 128;
  const int n0 = n_idx * 128;

  f32x4 acc[4][4] = {};
  const int lane = tid & 63, wave = tid >> 6;
  const int wm = (wave >> 1) * 64, wn = (wave & 1) * 64;
  const int lm = lane & 15, quad = lane >> 4;

  float4 pa[4];                          // A prefetch regs (2 chunks x 2 float4)

  auto loadA = [&](int kt) {
#pragma unroll
    for (int it = 0; it < 2; it++) {
      int idx = it * 256 + tid;
      int row = idx >> 2;
      int c = idx & 3;
      int cv = c ^ ((row >> 1) & 3);
      const float* src = obs + (size_t)(m0 + row) * 128 + kt * 32 + cv * 8;
      pa[it * 2] = *(const float4*)src;
      pa[it * 2 + 1] = *(const float4*)(src + 4);
    }
  };
  auto stageB = [&](int kt, int buf) {
    bf16* Bd = smem + buf * 8192 + 4096;
#pragma unroll
    for (int it = 0; it < 2; it++) {
      int idx = it * 256 + tid;
      int row = idx >> 2;
      int c = idx & 3;
      int cv = c ^ ((row >> 1) & 3);
      const bf16* gb = WpreLocT + (size_t)(n0 + row) * 128 + kt * 32 + cv * 8;
      __builtin_amdgcn_global_load_lds(GL(gb), SH(&Bd[(idx & ~63) * 8]), 16, 0, 0);
    }
  };
  auto commitA = [&](int buf) {
    bf16* Ad = smem + buf * 8192;
#pragma unroll
    for (int it = 0; it < 2; it++) {
      int idx = it * 256 + tid;
      int row = idx >> 2;
      int c = idx & 3;
      float4 f0 = pa[it * 2], f1 = pa[it * 2 + 1];
      bf16x8 v;
      v[0] = (bf16)f0.x; v[1] = (bf16)f0.y; v[2] = (bf16)f0.z; v[3] = (bf16)f0.w;
      v[4] = (bf16)f1.x; v[5] = (bf16)f1.y; v[6] = (bf16)f1.z; v[7] = (bf16)f1.w;
      *(bf16x8*)&Ad[row * 32 + c * 8] = v;
    }
  };
  auto compute = [&](int buf) {
    const bf16* Ar = smem + buf * 8192;
    const bf16* Br = smem + buf * 8192 + 4096;
    bf16x8 a[4], b[4];
#pragma unroll
    for (int i = 0; i < 4; i++) {
      int r = wm + lm + i * 16;
      a[i] = *(const bf16x8*)&Ar[r * 32 + ((quad ^ ((r >> 1) & 3)) * 8)];
    }
#pragma unroll
    for (int j = 0; j < 4; j++) {
      int r = wn + lm + j * 16;
      b[j] = *(const bf16x8*)&Br[r * 32 + ((quad ^ ((r >> 1) & 3)) * 8)];
    }
#pragma unroll
    for (int i = 0; i < 4; i++)
#pragma unroll
      for (int j = 0; j < 4; j++)
        acc[i][j] = MFMA(a[i], b[j], acc[i][j]);
  };

  loadA(0); stageB(0, 0); commitA(0);
  __syncthreads();
#pragma unroll
  for (int i = 0; i < 4; ++i) {
    if (i + 1 < 4) { loadA(i + 1); stageB(i + 1, (i + 1) & 1); }
    compute(i & 1);
    if (i + 1 < 4) commitA((i + 1) & 1);
    __syncthreads();
  }

  if (n_idx == 0) {
    bf16* xs = smem;                  // 16 x 136
    bf16* x2 = smem + 2176;           // 16 x 136
    bf16* gS = smem + 4352;           // 16 x 264
#pragma unroll
    for (int i = 0; i < 4; i++) {
      int sl = (wave >> 1) * 4 + i;
#pragma unroll
      for (int j = 0; j < 4; j++) {
        int col = wn + j * 16 + lm;
        float bb = biasPL[col];
        float v = 0.f;
#pragma unroll
        for (int r = 0; r < 4; r++) v += fmaxf(acc[i][j][r] + bb, 0.f);
        v += __shfl_xor(v, 16);
        v += __shfl_xor(v, 32);
        if (quad == 0) xs[sl * 136 + col] = (bf16)(v * 0.0625f);
        else if (quad == 1) xs[(8 + sl) * 136 + col] = (bf16)0.f;
      }
    }
    __syncthreads();
    {  // l0: xs -> x2
      f32x4 c2[2] = {};
#pragma unroll
      for (int ku = 0; ku < 4; ++ku) {
        bf16x8 a = *(const bf16x8*)&xs[lm * 136 + (ku * 4 + quad) * 8];
#pragma unroll
        for (int jn = 0; jn < 2; ++jn) {
          int col = (wave * 2 + jn) * 16 + lm;
          bf16x8 b = *(const bf16x8*)&Wg0T[(size_t)col * 128 + ku * 32 + quad * 8];
          c2[jn] = MFMA(a, b, c2[jn]);
        }
      }
      __syncthreads();
#pragma unroll
      for (int jn = 0; jn < 2; ++jn) {
        int col = (wave * 2 + jn) * 16 + lm;
        float bb = b_gcn[col];
#pragma unroll
        for (int r = 0; r < 4; ++r)
          x2[(quad * 4 + r) * 136 + col] = (bf16)fmaxf(c2[jn][r] + bb, 0.f);
      }
    }
    __syncthreads();
    {  // l1: x2 -> xs
      f32x4 c2[2] = {};
#pragma unroll
      for (int ku = 0; ku < 4; ++ku) {
        bf16x8 a = *(const bf16x8*)&x2[lm * 136 + (ku * 4 + quad) * 8];
#pragma unroll
        for (int jn = 0; jn < 2; ++jn) {
          int col = (wave * 2 + jn) * 16 + lm;
          bf16x8 b = *(const bf16x8*)&Wg1T[(size_t)col * 128 + ku * 32 + quad * 8];
          c2[jn] = MFMA(a, b, c2[jn]);
        }
      }
      __syncthreads();
#pragma unroll
      for (int jn = 0; jn < 2; ++jn) {
        int col = (wave * 2 + jn) * 16 + lm;
        float bb = b_gcn[128 + col];
#pragma unroll
        for (int r = 0; r < 4; ++r)
          xs[(quad * 4 + r) * 136 + col] = (bf16)fmaxf(c2[jn][r] + bb, 0.f);
      }
    }
    __syncthreads();
    {  // l2: xs -> gS
      f32x4 c3[4] = {};
#pragma unroll
      for (int ku = 0; ku < 4; ++ku) {
        bf16x8 a = *(const bf16x8*)&xs[lm * 136 + (ku * 4 + quad) * 8];
#pragma unroll
        for (int jn = 0; jn < 4; ++jn) {
          int col = (wave * 4 + jn) * 16 + lm;
          bf16x8 b = *(const bf16x8*)&WpostT[(size_t)col * 128 + ku * 32 + quad * 8];
          c3[jn] = MFMA(a, b, c3[jn]);
        }
      }
#pragma unroll
      for (int jn = 0; jn < 4; ++jn) {
        int col = (wave * 4 + jn) * 16 + lm;
        float bb = b_post[col];
#pragma unroll
        for (int r = 0; r < 4; ++r)
          gS[(quad * 4 + r) * 264 + col] = (bf16)fmaxf(c3[jn][r] + bb, 0.f);
      }
    }
    __syncthreads();
    {  // store g (8 samples x 256) -> gB; h computed by h_k
      int sample0 = m0 >> 4;
      int row = tid >> 5, col8 = (tid & 31) * 8;
      *(bf16x8*)&gB[(size_t)(sample0 + row) * 256 + col8] =
          *(const bf16x8*)&gS[row * 264 + col8];
    }
  } else {
#pragma unroll
    for (int i = 0; i < 4; i++)
#pragma unroll
      for (int j = 0; j < 4; j++) {
        int col = wn + j * 16 + lm;
        float bb = biasPL[n0 + col];
#pragma unroll
        for (int r = 0; r < 4; r++) {
          int row = wm + i * 16 + quad * 4 + r;
          smem[row * 128 + col] = (bf16)fmaxf(acc[i][j][r] + bb, 0.f);
        }
      }
    __syncthreads();
    const int coff = n0 - 128;
#pragma unroll
    for (int c = 0; c < 8; c++) {
      int ci = c * 256 + tid;
      int row = ci >> 4, col8 = (ci & 15) * 8;
      *(bf16x8*)&loc[(size_t)(m0 + row) * 256 + coff + col8] = *(const bf16x8*)&smem[row * 128 + col8];
    }
  }
}

// ---- h_k: hB = gB @ W1a + b1 (M=2048, N=512, K=256), 128^2 proven template ----
__global__ __launch_bounds__(256, 4) void h_k(
    const bf16* __restrict__ gB, const bf16* __restrict__ W1T,
    const float* __restrict__ b1, float* __restrict__ hB) {
  __shared__ bf16 smem[16384];
  const int tid = threadIdx.x;
  const int id = blockIdx.x;
  const int n_idx = id & 3;
  const int m0 = (id >> 2) * 128;
  const int n0 = n_idx * 128;

  f32x4 acc[4][4] = {};
  const int lane = tid & 63, wave = tid >> 6;
  const int wm = (wave >> 1) * 64, wn = (wave & 1) * 64;
  const int lm = lane & 15, quad = lane >> 4;

  auto stage = [&](int kt, int buf) {
    bf16* Ad = smem + buf * 8192;
    bf16* Bd = smem + buf * 8192 + 4096;
    int k0 = kt * 32;
#pragma unroll
    for (int it = 0; it < 2; it++) {
      int idx = it * 256 + tid;
      int row = idx >> 2;
      int c = idx & 3;
      int cv = c ^ ((row >> 1) & 3);
      int kk = k0 + cv * 8;
      const bf16* ga = gB + (size_t)(m0 + row) * 256 + kk;
      __builtin_amdgcn_global_load_lds(GL(ga), SH(&Ad[(idx & ~63) * 8]), 16, 0, 0);
      const bf16* gb = W1T + (size_t)(n0 + row) * 512 + kk;
      __builtin_amdgcn_global_load_lds(GL(gb), SH(&Bd[(idx & ~63) * 8]), 16, 0, 0);
    }
  };
  auto compute = [&](int buf) {
    const bf16* Ar = smem + buf * 8192;
    const bf16* Br = smem + buf * 8192 + 4096;
    bf16x8 a[4], b[4];
#pragma unroll
    for (int i = 0; i < 4; i++) {
      int r = wm + lm + i * 16;
      a[i] = *(const bf16x8*)&Ar[r * 32 + ((quad ^ ((r >> 1) & 3)) * 8)];
    }
#pragma unroll
    for (int j = 0; j < 4; j++) {
      int r = wn + lm + j * 16;
      b[j] = *(const bf16x8*)&Br[r * 32 + ((quad ^ ((r >> 1) & 3)) * 8)];
    }
#pragma unroll
    for (int i = 0; i < 4; i++)
#pragma unroll
      for (int j = 0; j < 4; j++)
        acc[i][j] = MFMA(a[i], b[j], acc[i][j]);
  };

  stage(0, 0);
  __syncthreads();
#pragma unroll 2
  for (int i = 0; i < 8; ++i) {
    if (i + 1 < 8) stage(i + 1, (i + 1) & 1);
    compute(i & 1);
    __syncthreads();
  }

#pragma unroll
  for (int i = 0; i < 4; i++)
#pragma unroll
    for (int j = 0; j < 4; j++) {
      int col = n0 + wn + j * 16 + lm;
      float bb = b1[col];
#pragma unroll
      for (int r = 0; r < 4; r++) {
        int row = m0 + wm + i * 16 + quad * 4 + r;
        hB[(size_t)row * 512 + col] = acc[i][j][r] + bb;
      }
    }
}

// ---- K3: 128x128 GEMM, BK=32, explicit LDS double-buffer (R8-proven) ----
template <bool HREP>
__global__ __launch_bounds__(256, 4) void gemm_k(
    const bf16* __restrict__ Ab, const bf16* __restrict__ BT,
    const float* __restrict__ bias, const float* __restrict__ hrep,
    bf16* __restrict__ C,
    const bf16* __restrict__ W3bT, const float* __restrict__ b3,
    float* __restrict__ outq) {
  __shared__ bf16 smem[16384];   // 2 x (A 4096 + B 4096)

  const int tid = threadIdx.x;
  const int id = blockIdx.x;
  const int s = id >> 3;
  const int n_idx = s & 3;
  const int m0 = ((id & 7) + 8 * (s >> 2)) * 128;
  const int n0 = n_idx * 128;

  f32x4 acc[4][4] = {};
  const int lane = tid & 63, wave = tid >> 6;
  const int wm = (wave >> 1) * 64, wn = (wave & 1) * 64;
  const int lm = lane & 15, quad = lane >> 4;

  auto stage = [&](int kt, int buf) {
    bf16* Ad = smem + buf * 8192;
    bf16* Bd = smem + buf * 8192 + 4096;
    int k0 = kt * 32;
#pragma unroll
    for (int it = 0; it < 2; it++) {
      int idx = it * 256 + tid;
      int row = idx >> 2;
      int c = idx & 3;
      int cv = c ^ ((row >> 1) & 3);
      int kk = k0 + cv * 8;
      const bf16* ga = Ab + (size_t)(m0 + row) * 256 + kk;
      __builtin_amdgcn_global_load_lds(GL(ga), SH(&Ad[(idx & ~63) * 8]), 16, 0, 0);
      const bf16* gb = BT + (size_t)(n0 + row) * 512 + 256 + kk;
      __builtin_amdgcn_global_load_lds(GL(gb), SH(&Bd[(idx & ~63) * 8]), 16, 0, 0);
    }
  };

  auto compute = [&](int buf) {
    const bf16* Ar = smem + buf * 8192;
    const bf16* Br = smem + buf * 8192 + 4096;
    bf16x8 a[4], b[4];
#pragma unroll
    for (int i = 0; i < 4; i++) {
      int r = wm + lm + i * 16;
      a[i] = *(const bf16x8*)&Ar[r * 32 + ((quad ^ ((r >> 1) & 3)) * 8)];
    }
#pragma unroll
    for (int j = 0; j < 4; j++) {
      int r = wn + lm + j * 16;
      b[j] = *(const bf16x8*)&Br[r * 32 + ((quad ^ ((r >> 1) & 3)) * 8)];
    }
#pragma unroll
    for (int i = 0; i < 4; i++)
#pragma unroll
      for (int j = 0; j < 4; j++)
        acc[i][j] = MFMA(a[i], b[j], acc[i][j]);
  };

  const int NIT = 8;
  stage(0, 0);
  __syncthreads();
#pragma unroll 2
  for (int i = 0; i < NIT; ++i) {
    if (i + 1 < NIT) stage(i + 1, (i + 1) & 1);
    compute(i & 1);
    __syncthreads();
  }

#pragma unroll
  for (int i = 0; i < 4; i++) {
    int sample = (m0 + wm + i * 16) >> 4;
#pragma unroll
    for (int j = 0; j < 4; j++) {
      int col = n0 + wn + j * 16 + lm;
      float hv = hrep[(size_t)sample * 512 + col];
#pragma unroll
      for (int r = 0; r < 4; r++) {
        int row = wm + i * 16 + quad * 4 + r;
        smem[row * 128 + (col - n0)] = (bf16)fmaxf(acc[i][j][r] + hv, 0.f);
      }
    }
  }
  __syncthreads();
#pragma unroll
  for (int c = 0; c < 8; c++) {
    int ci = c * 256 + tid;
    int row = ci >> 4, col8 = (ci & 15) * 8;
    *(bf16x8*)&C[(size_t)(m0 + row) * 512 + n0 + col8] = *(const bf16x8*)&smem[row * 128 + col8];
  }
}

// ---- K4: 256x256 tile, BK=64, 8-phase counted-vmcnt schedule (m201-style) ----
// 512 thr (8 waves 2Mx4N), 128 KB LDS dbuf, 1 block/CU. Each buffer = 4 proven
// BK=32 sub-tiles {A_kh0, A_kh1, B_kh0, B_kh1} with the verified chunk-XOR
// swizzle. Per K-tile: 4 phases, each {ds_read frags; issue 1 half-stage into
// other buf; [vmcnt(4) at phases 1,3]; barrier; lgkmcnt(0); 16 MFMA; barrier}.
// vmcnt never drains to 0 mid-loop (2 half-tiles stay in flight).
// Epilogue: z2 -> 128 KB swizzled LDS, hi/lo W3 q-MFMA, atomicAdd (2 partials).
__global__ __launch_bounds__(512, 1) void k4_8ph(
    const bf16* __restrict__ Ab, const bf16* __restrict__ W2T,
    const float* __restrict__ b2, const bf16* __restrict__ W3bT,
    const float* __restrict__ b3, float* __restrict__ outq) {
  __shared__ bf16 smem[65536];          // 128 KB: 2 x {A16K,A16K,B16K,B16K}... 2 x 32768

  const int tid = threadIdx.x;
  const int id = blockIdx.x;
  const int n_idx = id >> 7;            // 0..1
  const int m0 = (id & 127) * 256;
  const int n0 = n_idx * 256;

  f32x4 acc[8][4] = {};
  const int lane = tid & 63, wave = tid >> 6;
  const int wm = (wave >> 2) * 128, wn = (wave & 3) * 64;
  const int lm = lane & 15, quad = lane >> 4;

  // stage one half-tile (matrix m: 0=A,1=B; K-half kh) of tile t into buf
  auto stageH = [&](int t, int m, int kh, int buf) {
    bf16* D = smem + buf * 32768 + m * 16384 + kh * 8192;
    const bf16* S = m ? W2T : Ab;
    int rbase = m ? n0 : m0;
#pragma unroll
    for (int it = 0; it < 2; it++) {
      int idx = it * 512 + tid;          // 1024 slots of 16B
      int row = idx >> 2;                // 0..255
      int c = idx & 3;
      int cv = c ^ ((row >> 1) & 3);
      const bf16* g = S + (size_t)(rbase + row) * 512 + t * 64 + kh * 32 + cv * 8;
      __builtin_amdgcn_global_load_lds(GL(g), SH(&D[(idx & ~63) * 8]), 16, 0, 0);
    }
  };
  auto dsrA = [&](bf16x8* a, int buf, int ihalf, int kh) {
    const bf16* Ar = smem + buf * 32768 + kh * 8192;
#pragma unroll
    for (int i = 0; i < 4; i++) {
      int r = wm + lm + (ihalf * 4 + i) * 16;
      a[i] = *(const bf16x8*)&Ar[r * 32 + ((quad ^ ((r >> 1) & 3)) * 8)];
    }
  };
  auto dsrB = [&](bf16x8* b, int buf, int kh) {
    const bf16* Br = smem + buf * 32768 + 16384 + kh * 8192;
#pragma unroll
    for (int j = 0; j < 4; j++) {
      int r = wn + lm + j * 16;
      b[j] = *(const bf16x8*)&Br[r * 32 + ((quad ^ ((r >> 1) & 3)) * 8)];
    }
  };
  auto mfma16 = [&](bf16x8* a, bf16x8* b, int ihalf) {
    __builtin_amdgcn_s_setprio(1);
#pragma unroll
    for (int i = 0; i < 4; i++)
#pragma unroll
      for (int j = 0; j < 4; j++)
        acc[ihalf * 4 + i][j] = MFMA(a[i], b[j], acc[ihalf * 4 + i][j]);
    __builtin_amdgcn_s_setprio(0);
  };

  // prologue: tile 0, all 4 halves (issue order fixes vmcnt FIFO accounting)
  stageH(0, 0, 0, 0); stageH(0, 1, 0, 0); stageH(0, 0, 1, 0); stageH(0, 1, 1, 0);
  WAIT_VM(4);                            // kh0 halves landed (4 newest = kh1)
  BARRIER();

  const int NT = 8;                      // K=512 / BK=64
  for (int t = 0; t < NT - 1; ++t) {
    int cur = t & 1, nxt = cur ^ 1;
    bf16x8 a[4], b[4];
    // P0: a[0..3]+b kh0 | stage A(t+1,kh0)
    dsrA(a, cur, 0, 0); dsrB(b, cur, 0);
    stageH(t + 1, 0, 0, nxt);
    BARRIER(); WAIT_LGKM0();
    mfma16(a, b, 0);
    BARRIER();
    // P1: a[4..7] kh0 | stage B(t+1,kh0) | vmcnt(4): kh1(t) landed
    dsrA(a, cur, 1, 0);
    stageH(t + 1, 1, 0, nxt);
    WAIT_VM(4);
    BARRIER(); WAIT_LGKM0();
    mfma16(a, b, 1);
    BARRIER();
    // P2: a[0..3]+b kh1 | stage A(t+1,kh1)
    dsrA(a, cur, 0, 1); dsrB(b, cur, 1);
    stageH(t + 1, 0, 1, nxt);
    BARRIER(); WAIT_LGKM0();
    mfma16(a, b, 0);
    BARRIER();
    // P3: a[4..7] kh1 | stage B(t+1,kh1) | vmcnt(4): kh0(t+1) landed
    dsrA(a, cur, 1, 1);
    stageH(t + 1, 1, 1, nxt);
    WAIT_VM(4);
    BARRIER(); WAIT_LGKM0();
    mfma16(a, b, 1);
    BARRIER();
  }
  {                                      // tile NT-1 (cur = 1), no staging
    const int cur = (NT - 1) & 1;
    bf16x8 a[4], b[4];
    dsrA(a, cur, 0, 0); dsrB(b, cur, 0);
    BARRIER(); WAIT_LGKM0();
    mfma16(a, b, 0);
    BARRIER();
    dsrA(a, cur, 1, 0);
    WAIT_VM(0);                          // kh1 of last tile landed
    BARRIER(); WAIT_LGKM0();
    mfma16(a, b, 1);
    BARRIER();
    dsrA(a, cur, 0, 1); dsrB(b, cur, 1);
    BARRIER(); WAIT_LGKM0();
    mfma16(a, b, 0);
    BARRIER();
    dsrA(a, cur, 1, 1);
    BARRIER(); WAIT_LGKM0();
    mfma16(a, b, 1);
    BARRIER();
  }

  // ---- epilogue: z2 (256x256) -> swizzled LDS; hi/lo W3 q-MFMA; atomics ----
  __syncthreads();
#pragma unroll
  for (int i = 0; i < 8; i++)
#pragma unroll
    for (int j = 0; j < 4; j++) {
      int col = wn + j * 16 + lm;        // 0..255
      float bb = b2[n0 + col];
#pragma unroll
      for (int r = 0; r < 4; r++) {
        int row = wm + i * 16 + quad * 4 + r;   // 0..255
        int pc = (col >> 3) ^ (row & 7);
        smem[row * 256 + pc * 8 + (col & 7)] = (bf16)fmaxf(acc[i][j][r] + bb, 0.f);
      }
    }
  __syncthreads();
  bf16x8 w3h[8], w3l[8];
#pragma unroll
  for (int kt = 0; kt < 8; kt++) {
    w3h[kt] = *(const bf16x8*)&W3bT[lm * 512 + n0 + kt * 32 + quad * 8];
    w3l[kt] = *(const bf16x8*)&W3bT[8192 + lm * 512 + n0 + kt * 32 + quad * 8];
  }
  f32x4 qacc[2] = {};
#pragma unroll
  for (int it = 0; it < 2; it++)
#pragma unroll
    for (int kt = 0; kt < 8; kt++) {
      int rr = wave * 32 + it * 16 + lm;
      bf16x8 a = *(const bf16x8*)&smem[rr * 256 + (((kt * 4 + quad) ^ (rr & 7)) * 8)];
      qacc[it] = MFMA(a, w3h[kt], qacc[it]);
      qacc[it] = MFMA(a, w3l[kt], qacc[it]);
    }
  float qb = (n_idx == 0 && lm < 8) ? b3[lm] : 0.f;
  if (lm < 8) {
#pragma unroll
    for (int it = 0; it < 2; it++)
#pragma unroll
      for (int r = 0; r < 4; r++) {
        int row = m0 + wave * 32 + it * 16 + quad * 4 + r;
        atomicAdd(&outq[(size_t)row * 8 + lm], qacc[it][r] + qb);
      }
  }
}

extern "C" void kernel_launch(void* const* d_in, const int* in_sizes, int n_in,
                              void* d_out, int out_size, void* d_ws, size_t ws_size,
                              hipStream_t stream) {
  const float* obs    = (const float*)d_in[0];
  const float* W_pre  = (const float*)d_in[1];
  const float* b_pre  = (const float*)d_in[2];
  const float* W_gcn  = (const float*)d_in[3];
  const float* b_gcn  = (const float*)d_in[4];
  const float* W_post = (const float*)d_in[5];
  const float* b_post = (const float*)d_in[6];
  const float* W_loc  = (const float*)d_in[7];
  const float* b_loc  = (const float*)d_in[8];
  const float* W1     = (const float*)d_in[9];
  const float* b1     = (const float*)d_in[10];
  const float* W2     = (const float*)d_in[11];
  const float* b2     = (const float*)d_in[12];
  const float* W3     = (const float*)d_in[13];
  const float* b3     = (const float*)d_in[14];
  float* out = (float*)d_out;

  char* p = (char*)d_ws;
  auto alloc = [&](size_t bytes) { char* r = p; p += (bytes + 255) & ~(size_t)255; return r; };
  bf16* WpreLocT = (bf16*)alloc(384 * 128 * 2);
  float* biasPL  = (float*)alloc(384 * 4);
  bf16* Wg0T   = (bf16*)alloc(128 * 128 * 2);
  bf16* Wg1T   = (bf16*)alloc(128 * 128 * 2);
  bf16* WpostT = (bf16*)alloc(256 * 128 * 2);
  bf16* W1T    = (bf16*)alloc(512 * 512 * 2);
  bf16* W2T    = (bf16*)alloc(512 * 512 * 2);
  bf16* W3bT   = (bf16*)alloc(2 * 16 * 512 * 2);
  bf16* gB     = (bf16*)alloc((size_t)2048 * 256 * 2);
  bf16* locB   = (bf16*)alloc((size_t)32768 * 256 * 2);
  float* hB    = (float*)alloc((size_t)2048 * 512 * 4);
  bf16* z1B    = (bf16*)alloc((size_t)32768 * 512 * 2);

  // P: only k1c-critical prep (small transposes + bias)
  prep_all<<<449, 256, 0, stream>>>(W_pre, W_loc, W_gcn, W_post,
                                    WpreLocT, Wg0T, Wg1T, WpostT,
                                    b_pre, b_loc, biasPL);
  // K1+chain -> g, loc; blocks 768+ do W1/W2 transpose, W3 hi/lo, d_out zero
  k1c<<<961, 256, 0, stream>>>(obs, WpreLocT, biasPL,
                               Wg0T, Wg1T, WpostT, b_gcn, b_post,
                               gB, locB,
                               W1, W2, W1T, W2T, W3, W3bT, out);
  // h = g @ W1a + b1 (dense 128^2 tile GEMM, 64 blocks)
  h_k<<<64, 256, 0, stream>>>(gB, W1T, b1, hB);
  // K3: z1 = relu(loc @ W1b + h_rep), K=256, double-buffered (R8-proven)
  gemm_k<true><<<1024, 256, 0, stream>>>(locB, W1T, nullptr, hB, z1B,
                                         nullptr, nullptr, nullptr);
  // K4: z2 = relu(z1 @ W2 + b2) + MFMA q-head, 256^2 8-phase counted-vmcnt
  k4_8ph<<<256, 512, 0, stream>>>(z1B, W2T, b2, W3bT, b3, out);
}